// Round 4
// baseline (286.568 us; speedup 1.0000x reference)
//
#include <hip/hip_runtime.h>
#include <math.h>

#define H_HEADS 33
#define C_CH    16
#define HC      528      // H_HEADS * C_CH
#define JG      11       // head groups of 3 (48 cols each) for h
#define JGT     13       // + 2 groups: att_src logits, att_dst logits
#define F_IN    128
#define NEG_SLOPE 0.2f

typedef short  bf16x8  __attribute__((ext_vector_type(8)));
typedef float  floatx4 __attribute__((ext_vector_type(4)));

__device__ inline unsigned short f2bf(float f) {   // RNE float->bf16
    unsigned int u = __float_as_uint(f);
    unsigned int r = u + 0x7fffu + ((u >> 16) & 1u);
    return (unsigned short)(r >> 16);
}
__device__ inline float bf2f(unsigned short u) {
    return __uint_as_float((unsigned int)u << 16);
}

// ---------------------------------------------------------------------------
// K0: Wt[0..527] = bf16(W^T); rows 528..623 = attention-logit GEMM columns:
//  row 528+h: Ws[k,h] = sum_c W[k][h*16+c]*att_src[h][c]
//  row 576+h: Wd[k,h] likewise with att_dst (other rows zero).
// ---------------------------------------------------------------------------
__global__ void prep_w_kernel(const float* __restrict__ W,
                              const float* __restrict__ att_src,
                              const float* __restrict__ att_dst,
                              unsigned short* __restrict__ Wt)
{
    int g = blockIdx.x * blockDim.x + threadIdx.x;
    if (g < F_IN * HC) {
        int k = g / HC, n = g % HC;
        Wt[n * F_IN + k] = f2bf(W[g]);
    } else if (g < F_IN * HC + 96 * F_IN) {
        int gg = g - F_IN * HC;
        int nl = gg >> 7, k = gg & 127;
        int grp = nl / 48, h = nl % 48;
        float v = 0.f;
        if (h < H_HEADS) {
            const float* att = grp ? att_dst : att_src;
            const float* wr  = W + (size_t)k * HC + h * C_CH;
            #pragma unroll
            for (int c = 0; c < C_CH; ++c) v += wr[c] * att[h * C_CH + c];
        }
        Wt[(size_t)(HC + nl) * F_IN + k] = f2bf(v);
    }
}

// ---------------------------------------------------------------------------
// K1: h = x @ W via MFMA 16x16x32 bf16. One block per 64 rows; f32 x-tile
// staged once (bf16 convert fused), A fragments in registers, 13 groups
// looped internally. Bs staging is REGISTER DOUBLE-BUFFERED: j+1's three
// uint4 Wt loads issue between the LDS write and the MFMA phase of j, so
// L2 latency hides under MFMA+epilogue (round-2 counters showed the stage
// sat serially between barriers: MfmaUtil 2.5%).
// Groups 0..10 -> hb column-blocked [j][row][48]; group 11 -> a_src[row][33];
// group 12 -> ad2 float2[row][33].x (a_dst).
// ---------------------------------------------------------------------------
#define LDA 136
__global__ __launch_bounds__(256) void gemm_att_kernel(
    const float* __restrict__ x, const unsigned short* __restrict__ Wt,
    unsigned short* __restrict__ hb,
    float* __restrict__ a_src, float* __restrict__ ad2, int N)
{
    __shared__ unsigned short As[64][LDA];   // As[m][k]
    __shared__ unsigned short Bs[48][LDA];   // Bs[n][k] (= Wt rows)

    const int tid  = threadIdx.x;
    const int lane = tid & 63;
    const int wave = tid >> 6;
    const int lm   = lane & 15;
    const int kc   = lane >> 4;
    const int m0   = blockIdx.x * 64;
    const size_t segN = (size_t)N * 48;

    // stage As from f32 x, converting: 64 rows x 32 float4 chunks
    for (int e = tid; e < 64 * 32; e += 256) {
        int r = e >> 5, c = e & 31;
        int gr = m0 + r;
        float4 v = (gr < N) ? ((const float4*)(x + (size_t)gr * F_IN))[c]
                            : make_float4(0.f, 0.f, 0.f, 0.f);
        unsigned int lo = (unsigned int)f2bf(v.x) | ((unsigned int)f2bf(v.y) << 16);
        unsigned int hi = (unsigned int)f2bf(v.z) | ((unsigned int)f2bf(v.w) << 16);
        *(uint2*)&As[r][c * 4] = make_uint2(lo, hi);
    }

    // prefetch j=0 B-tile into registers (Wt rows are contiguous uint4s:
    // element e of tile j sits at wp[j*768 + e])
    const uint4* wp = (const uint4*)Wt;
    uint4 rb0 = wp[tid], rb1 = wp[tid + 256], rb2 = wp[tid + 512];

    __syncthreads();

    // A fragments live in registers across all 13 group iterations
    const int arow = wave * 16 + lm;
    bf16x8 afrag[4];
    #pragma unroll
    for (int ks = 0; ks < 4; ++ks)
        afrag[ks] = *(const bf16x8*)&As[arow][ks * 32 + kc * 8];

    #pragma unroll 1
    for (int j = 0; j < JGT; ++j) {
        __syncthreads();   // previous iteration's Bs reads done
        *(uint4*)&Bs[tid >> 4][(tid & 15) * 8] = rb0;
        { int e = tid + 256; *(uint4*)&Bs[e >> 4][(e & 15) * 8] = rb1; }
        { int e = tid + 512; *(uint4*)&Bs[e >> 4][(e & 15) * 8] = rb2; }
        if (j + 1 < JGT) {
            int b = (j + 1) * 768;
            rb0 = wp[b + tid]; rb1 = wp[b + tid + 256]; rb2 = wp[b + tid + 512];
        }
        __syncthreads();

        floatx4 acc[3] = {};
        #pragma unroll
        for (int ks = 0; ks < 4; ++ks) {
            #pragma unroll
            for (int t = 0; t < 3; ++t) {
                bf16x8 b = *(const bf16x8*)&Bs[t * 16 + lm][ks * 32 + kc * 8];
                acc[t] = __builtin_amdgcn_mfma_f32_16x16x32_bf16(afrag[ks], b, acc[t], 0, 0, 0);
            }
        }

        // C/D layout: col = lane&15, row = (lane>>4)*4 + reg
        #pragma unroll
        for (int t = 0; t < 3; ++t) {
            #pragma unroll
            for (int rr = 0; rr < 4; ++rr) {
                const int row = m0 + wave * 16 + kc * 4 + rr;
                if (row >= N) continue;
                if (j < JG) {
                    hb[(size_t)j * segN + (size_t)row * 48 + t * 16 + lm] =
                        f2bf(acc[t][rr]);
                } else {
                    const int col = t * 16 + lm;
                    if (col < H_HEADS) {
                        if (j == JG) a_src[(size_t)row * H_HEADS + col] = acc[t][rr];
                        else         ad2[(size_t)row * 66 + col * 2]    = acc[t][rr];
                    }
                }
            }
        }
    }
}

// ---------------------------------------------------------------------------
// Counting sort of edges (incl. self loops) by src (for aggregate's h gather
// locality) AND by dst (for atomic-free denom).
// ---------------------------------------------------------------------------
__global__ void hist_kernel(const int* __restrict__ ei,
                            int* __restrict__ hist_s, int* __restrict__ hist_d,
                            int E, int Et)
{
    int g = blockIdx.x * blockDim.x + threadIdx.x;
    if (g >= Et) return;
    int src, dst;
    if (g < E) { src = ei[g]; dst = ei[E + g]; }
    else       { src = dst = g - E; }
    atomicAdd(&hist_s[src], 1);
    atomicAdd(&hist_d[dst], 1);
}

// exclusive scan, 16 elems/thread; grid=2: block0 scans hist_s->cur_s,
// block1 scans hist_d->cur_d+off_d (the two scans run concurrently).
#define VPT 16
__global__ __launch_bounds__(1024) void scan_kernel(
    const int* __restrict__ hist_s, int* __restrict__ cur_s,
    const int* __restrict__ hist_d, int* __restrict__ cur_d,
    int* __restrict__ off_d, int n)
{
    const int* hist = blockIdx.x ? hist_d : hist_s;
    int* o0 = blockIdx.x ? cur_d : cur_s;
    int* o1 = blockIdx.x ? off_d : (int*)nullptr;

    __shared__ int warp_sums[16];
    __shared__ int s_carry;
    const int tid  = threadIdx.x;
    const int lane = tid & 63, wid = tid >> 6;
    if (tid == 0) s_carry = 0;
    __syncthreads();
    const int nC = (n + VPT - 1) / VPT;
    for (int base = 0; base < nC; base += 1024) {
        int iC = base + tid;
        int v[VPT];
        bool full = (iC * VPT + VPT <= n);
        if (full) {
            #pragma unroll
            for (int qq = 0; qq < VPT / 4; ++qq)
                *(int4*)&v[qq * 4] = ((const int4*)hist)[iC * (VPT / 4) + qq];
        } else {
            #pragma unroll
            for (int k = 0; k < VPT; ++k)
                v[k] = (iC * VPT + k < n) ? hist[iC * VPT + k] : 0;
        }
        int tsum = 0;
        #pragma unroll
        for (int k = 0; k < VPT; ++k) tsum += v[k];
        int s = tsum;
        #pragma unroll
        for (int dd = 1; dd < 64; dd <<= 1) {
            int t = __shfl_up(s, dd);
            if (lane >= dd) s += t;
        }
        if (lane == 63) warp_sums[wid] = s;
        __syncthreads();
        if (tid < 16) {
            int ws = warp_sums[tid];
            #pragma unroll
            for (int dd = 1; dd < 16; dd <<= 1) {
                int t = __shfl_up(ws, dd);
                if (tid >= dd) ws += t;
            }
            warp_sums[tid] = ws;
        }
        __syncthreads();
        int excl = s_carry + (wid ? warp_sums[wid - 1] : 0) + (s - tsum);
        int o[VPT];
        #pragma unroll
        for (int k = 0; k < VPT; ++k) { o[k] = excl; excl += v[k]; }
        if (full) {
            #pragma unroll
            for (int qq = 0; qq < VPT / 4; ++qq) {
                ((int4*)o0)[iC * (VPT / 4) + qq] = *(int4*)&o[qq * 4];
                if (o1) ((int4*)o1)[iC * (VPT / 4) + qq] = *(int4*)&o[qq * 4];
            }
        } else {
            for (int k = 0; k < VPT; ++k)
                if (iC * VPT + k < n) {
                    o0[iC * VPT + k] = o[k];
                    if (o1) o1[iC * VPT + k] = o[k];
                }
        }
        __syncthreads();
        if (tid == 0) s_carry = s_carry + warp_sums[15];
        __syncthreads();
    }
}

__global__ void scatter_kernel(const int* __restrict__ ei,
                               int* __restrict__ cur_s, int* __restrict__ cur_d,
                               int2* __restrict__ e2,
                               int* __restrict__ ss2, int E, int Et)
{
    int g = blockIdx.x * blockDim.x + threadIdx.x;
    if (g >= Et) return;
    int src, dst;
    if (g < E) { src = ei[g]; dst = ei[E + g]; }
    else       { src = dst = g - E; }
    int ps = atomicAdd(&cur_s[src], 1);
    e2[ps] = make_int2(src, dst);
    int pd = atomicAdd(&cur_d[dst], 1);
    ss2[pd] = src;
}

// ---------------------------------------------------------------------------
// K2: denom, atomic-free. One wave per destination node (contiguous run in
// dst-sorted ss2). Lanes 0..32 = heads. Writes the interleaved float2
// {a_dst, 1/(denom+eps)} so aggregate's alpha phase does ONE 8B load and a
// multiply (no divide) per (edge,head).
// ---------------------------------------------------------------------------
__global__ __launch_bounds__(256) void denom_kernel(
    const int* __restrict__ off_d, const int* __restrict__ ss2,
    const float* __restrict__ a_src, float* __restrict__ ad2, int N, int Et)
{
    const int d = blockIdx.x * 4 + (threadIdx.x >> 6);
    if (d >= N) return;
    const int lane = threadIdx.x & 63;
    const int beg = off_d[d];
    const int end = (d + 1 < N) ? off_d[d + 1] : Et;
    const float ad = (lane < H_HEADS) ? ad2[(size_t)d * 66 + lane * 2] : 0.f;
    float acc = 0.f;
    int src = ss2[beg];
    for (int e = beg; e < end; ++e) {
        int nxt = (e + 1 < end) ? ss2[e + 1] : 0;
        float v = (lane < H_HEADS) ? (a_src[src * H_HEADS + lane] + ad) : 0.f;
        v = v > 0.f ? v : NEG_SLOPE * v;
        acc += __expf(v);
        src = nxt;
    }
    if (lane < H_HEADS)
        ((float2*)ad2)[(size_t)d * 33 + lane] =
            make_float2(ad, 1.0f / (acc + 1e-16f));
}

// ---------------------------------------------------------------------------
// K3: 64 src-sorted edges/block. Phase 1: 64x33 alphas into LDS (one float2
// load + exp + mul each). Phase 2: 8 lanes/edge, each lane owns a CHANNEL
// PAIR via uint loads (halves VMEM instruction count vs 2B loads; bf16
// unpack is 1 VALU op per value). Two atomics per lane per edge.
// ---------------------------------------------------------------------------
#define EPB 64
__global__ __launch_bounds__(256) void aggregate_kernel(
    const int2* __restrict__ e2,
    const float* __restrict__ a_src, const float* __restrict__ ad2,
    const unsigned short* __restrict__ hb,
    float* __restrict__ out, int N, int Et)
{
    __shared__ int   s_src[EPB], s_dst[EPB];
    __shared__ float s_alpha[EPB][H_HEADS];

    // bijective XCD-chunked block swizzle (m204 formula)
    const int nwg = gridDim.x;
    const int q = nwg >> 3, r = nwg & 7;
    const int xcd = blockIdx.x & 7, idx = blockIdx.x >> 3;
    const int bid = (xcd < r ? xcd * (q + 1) : r * (q + 1) + (xcd - r) * q) + idx;

    const int tid = threadIdx.x;
    const int e0  = bid * EPB;
    const size_t segN = (size_t)N * 48;

    if (tid < EPB) {
        int e = e0 + tid;
        int2 v = (e < Et) ? e2[e] : make_int2(0, 0);
        s_src[tid] = v.x; s_dst[tid] = v.y;
    }
    __syncthreads();

    for (int i = tid; i < EPB * H_HEADS; i += 256) {
        int el = i / H_HEADS, hd = i - el * H_HEADS;
        if (e0 + el < Et) {
            int src = s_src[el], dst = s_dst[el];
            float2 di = ((const float2*)ad2)[(size_t)dst * 33 + hd];
            float v = a_src[src * H_HEADS + hd] + di.x;
            v = v > 0.f ? v : NEG_SLOPE * v;
            s_alpha[el][hd] = __expf(v) * di.y;
        }
    }
    __syncthreads();

    const int elh = tid >> 3, cp = tid & 7;
    #pragma unroll 1
    for (int el = elh; el < EPB; el += 32) {
        int e = e0 + el;
        if (e >= Et) break;
        int src = s_src[el], dst = s_dst[el];
        const unsigned short* hp = hb + (size_t)src * 48 + cp * 2;
        float acc0 = 0.f, acc1 = 0.f;
        #pragma unroll
        for (int j = 0; j < JG; ++j) {
            const unsigned short* pj = hp + (size_t)j * segN;
            unsigned int w0 = *(const unsigned int*)(pj);
            unsigned int w1 = *(const unsigned int*)(pj + 16);
            unsigned int w2 = *(const unsigned int*)(pj + 32);
            float a0 = s_alpha[el][j * 3 + 0];
            float a1 = s_alpha[el][j * 3 + 1];
            float a2 = s_alpha[el][j * 3 + 2];
            acc0 += a0 * __uint_as_float(w0 << 16)
                  + a1 * __uint_as_float(w1 << 16)
                  + a2 * __uint_as_float(w2 << 16);
            acc1 += a0 * __uint_as_float(w0 & 0xffff0000u)
                  + a1 * __uint_as_float(w1 & 0xffff0000u)
                  + a2 * __uint_as_float(w2 & 0xffff0000u);
        }
        atomicAdd(&out[dst * C_CH + cp * 2],     acc0);
        atomicAdd(&out[dst * C_CH + cp * 2 + 1], acc1);
    }
}

// K4: out = tanh(out/H + bias), in place
__global__ void finalize_kernel(float* __restrict__ out,
                                const float* __restrict__ bias, int total)
{
    int g = blockIdx.x * blockDim.x + threadIdx.x;
    if (g >= total) return;
    out[g] = tanhf(out[g] * (1.0f / 33.0f) + bias[g & 15]);
}

// ---------------------------------------------------------------------------
extern "C" void kernel_launch(void* const* d_in, const int* in_sizes, int n_in,
                              void* d_out, int out_size, void* d_ws, size_t ws_size,
                              hipStream_t stream)
{
    const float* x       = (const float*)d_in[0];
    const int*   ei      = (const int*)  d_in[1];
    const float* W       = (const float*)d_in[2];
    const float* att_src = (const float*)d_in[3];
    const float* att_dst = (const float*)d_in[4];
    const float* bias    = (const float*)d_in[5];
    float* out = (float*)d_out;

    const int N  = in_sizes[0] / F_IN;   // 50000
    const int E  = in_sizes[1] / 2;      // 320000
    const int Et = E + N;                // with self loops

    // workspace layout (all 16B-aligned for these sizes)
    unsigned short* hb = (unsigned short*)d_ws;          // 11 segments [N][48]
    float* a_src  = (float*)(hb + (size_t)N * HC);       // [N][33]
    float* ad2    = a_src + (size_t)N * H_HEADS;         // float2[N][33] a_dst|inv
    int2*  e2     = (int2*)(ad2 + (size_t)N * 66);       // [Et] (src,dst)
    int*   ss2    = (int*)(e2 + Et);
    int*   hist_s = ss2 + Et;
    int*   hist_d = hist_s + N;
    int*   cur_s  = hist_d + N;
    int*   cur_d  = cur_s + N;
    int*   off_d  = cur_d + N;
    unsigned short* Wt = (unsigned short*)(off_d + N);   // [624][128]

    hipMemsetAsync(d_out, 0, (size_t)out_size * sizeof(float), stream);
    hipMemsetAsync(hist_s, 0, 2 * (size_t)N * sizeof(int), stream);  // hist_s + hist_d

    int prepTot = F_IN * HC + 96 * F_IN;
    prep_w_kernel<<<(prepTot + 255) / 256, 256, 0, stream>>>(W, att_src, att_dst, Wt);

    gemm_att_kernel<<<(N + 63) / 64, 256, 0, stream>>>(x, Wt, hb, a_src, ad2, N);

    hist_kernel<<<(Et + 255) / 256, 256, 0, stream>>>(ei, hist_s, hist_d, E, Et);
    scan_kernel<<<2, 1024, 0, stream>>>(hist_s, cur_s, hist_d, cur_d, off_d, N);
    scatter_kernel<<<(Et + 255) / 256, 256, 0, stream>>>(ei, cur_s, cur_d,
                                                         e2, ss2, E, Et);

    denom_kernel<<<(N + 3) / 4, 256, 0, stream>>>(off_d, ss2, a_src, ad2, N, Et);

    aggregate_kernel<<<(Et + EPB - 1) / EPB, 256, 0, stream>>>(
        e2, a_src, ad2, hb, out, N, Et);

    int totO = N * C_CH;
    finalize_kernel<<<(totO + 255) / 256, 256, 0, stream>>>(out, bias, totO);
}

// Round 5
// 272.974 us; speedup vs baseline: 1.0498x; 1.0498x over previous
//
#include <hip/hip_runtime.h>
#include <math.h>

#define H_HEADS 33
#define C_CH    16
#define HC      528      // H_HEADS * C_CH
#define JG      11       // head groups of 3 (48 cols each) for h
#define JGT     13       // + 2 groups: att_src logits, att_dst logits
#define F_IN    128
#define NEG_SLOPE 0.2f

typedef short  bf16x8  __attribute__((ext_vector_type(8)));
typedef float  floatx4 __attribute__((ext_vector_type(4)));

__device__ inline unsigned short f2bf(float f) {   // RNE float->bf16
    unsigned int u = __float_as_uint(f);
    unsigned int r = u + 0x7fffu + ((u >> 16) & 1u);
    return (unsigned short)(r >> 16);
}
__device__ inline float bflo(unsigned int u) {
    return __uint_as_float(u << 16);
}
__device__ inline float bfhi(unsigned int u) {
    return __uint_as_float(u & 0xffff0000u);
}

// ---------------------------------------------------------------------------
// K0: Wt[0..527] = bf16(W^T); rows 528..623 = attention-logit GEMM columns:
//  row 528+h: Ws[k,h] = sum_c W[k][h*16+c]*att_src[h][c]
//  row 576+h: Wd[k,h] likewise with att_dst (other rows zero).
// ---------------------------------------------------------------------------
__global__ void prep_w_kernel(const float* __restrict__ W,
                              const float* __restrict__ att_src,
                              const float* __restrict__ att_dst,
                              unsigned short* __restrict__ Wt)
{
    int g = blockIdx.x * blockDim.x + threadIdx.x;
    if (g < F_IN * HC) {
        int k = g / HC, n = g % HC;
        Wt[n * F_IN + k] = f2bf(W[g]);
    } else if (g < F_IN * HC + 96 * F_IN) {
        int gg = g - F_IN * HC;
        int nl = gg >> 7, k = gg & 127;
        int grp = nl / 48, h = nl % 48;
        float v = 0.f;
        if (h < H_HEADS) {
            const float* att = grp ? att_dst : att_src;
            const float* wr  = W + (size_t)k * HC + h * C_CH;
            #pragma unroll
            for (int c = 0; c < C_CH; ++c) v += wr[c] * att[h * C_CH + c];
        }
        Wt[(size_t)(HC + nl) * F_IN + k] = f2bf(v);
    }
}

// ---------------------------------------------------------------------------
// K1: h = x @ W via MFMA 16x16x32 bf16. One block per 64 rows; f32 x-tile
// staged once (bf16 convert fused), A fragments in registers, 13 groups
// looped internally. Bs staging register double-buffered (j+1's Wt loads
// issue under j's MFMA+epilogue).
// Groups 0..10 -> hb column-blocked [j][row][48]; group 11 -> a_src[row][33];
// group 12 -> a_dstc[row][33] (compact, fully-covered stores; denom folds it
// into the float2 ad2 array later).
// ---------------------------------------------------------------------------
#define LDA 136
__global__ __launch_bounds__(256) void gemm_att_kernel(
    const float* __restrict__ x, const unsigned short* __restrict__ Wt,
    unsigned short* __restrict__ hb,
    float* __restrict__ a_src, float* __restrict__ a_dstc, int N)
{
    __shared__ unsigned short As[64][LDA];   // As[m][k]
    __shared__ unsigned short Bs[48][LDA];   // Bs[n][k] (= Wt rows)

    const int tid  = threadIdx.x;
    const int lane = tid & 63;
    const int wave = tid >> 6;
    const int lm   = lane & 15;
    const int kc   = lane >> 4;
    const int m0   = blockIdx.x * 64;
    const size_t segN = (size_t)N * 48;

    // stage As from f32 x, converting: 64 rows x 32 float4 chunks
    for (int e = tid; e < 64 * 32; e += 256) {
        int r = e >> 5, c = e & 31;
        int gr = m0 + r;
        float4 v = (gr < N) ? ((const float4*)(x + (size_t)gr * F_IN))[c]
                            : make_float4(0.f, 0.f, 0.f, 0.f);
        unsigned int lo = (unsigned int)f2bf(v.x) | ((unsigned int)f2bf(v.y) << 16);
        unsigned int hi = (unsigned int)f2bf(v.z) | ((unsigned int)f2bf(v.w) << 16);
        *(uint2*)&As[r][c * 4] = make_uint2(lo, hi);
    }

    // prefetch j=0 B-tile into registers (Wt rows are contiguous uint4s)
    const uint4* wp = (const uint4*)Wt;
    uint4 rb0 = wp[tid], rb1 = wp[tid + 256], rb2 = wp[tid + 512];

    __syncthreads();

    // A fragments live in registers across all 13 group iterations
    const int arow = wave * 16 + lm;
    bf16x8 afrag[4];
    #pragma unroll
    for (int ks = 0; ks < 4; ++ks)
        afrag[ks] = *(const bf16x8*)&As[arow][ks * 32 + kc * 8];

    #pragma unroll 1
    for (int j = 0; j < JGT; ++j) {
        __syncthreads();   // previous iteration's Bs reads done
        *(uint4*)&Bs[tid >> 4][(tid & 15) * 8] = rb0;
        { int e = tid + 256; *(uint4*)&Bs[e >> 4][(e & 15) * 8] = rb1; }
        { int e = tid + 512; *(uint4*)&Bs[e >> 4][(e & 15) * 8] = rb2; }
        if (j + 1 < JGT) {
            int b = (j + 1) * 768;
            rb0 = wp[b + tid]; rb1 = wp[b + tid + 256]; rb2 = wp[b + tid + 512];
        }
        __syncthreads();

        floatx4 acc[3] = {};
        #pragma unroll
        for (int ks = 0; ks < 4; ++ks) {
            #pragma unroll
            for (int t = 0; t < 3; ++t) {
                bf16x8 b = *(const bf16x8*)&Bs[t * 16 + lm][ks * 32 + kc * 8];
                acc[t] = __builtin_amdgcn_mfma_f32_16x16x32_bf16(afrag[ks], b, acc[t], 0, 0, 0);
            }
        }

        // C/D layout: col = lane&15, row = (lane>>4)*4 + reg
        #pragma unroll
        for (int t = 0; t < 3; ++t) {
            #pragma unroll
            for (int rr = 0; rr < 4; ++rr) {
                const int row = m0 + wave * 16 + kc * 4 + rr;
                if (row >= N) continue;
                if (j < JG) {
                    hb[(size_t)j * segN + (size_t)row * 48 + t * 16 + lm] =
                        f2bf(acc[t][rr]);
                } else {
                    const int col = t * 16 + lm;
                    if (col < H_HEADS) {
                        float* dstp = (j == JG) ? a_src : a_dstc;
                        dstp[(size_t)row * H_HEADS + col] = acc[t][rr];
                    }
                }
            }
        }
    }
}

// ---------------------------------------------------------------------------
// Counting sort of edges (incl. self loops) by src (for aggregate's h gather
// locality) AND by dst (for atomic-free denom).
// ---------------------------------------------------------------------------
__global__ void hist_kernel(const int* __restrict__ ei,
                            int* __restrict__ hist_s, int* __restrict__ hist_d,
                            int E, int Et)
{
    int g = blockIdx.x * blockDim.x + threadIdx.x;
    if (g >= Et) return;
    int src, dst;
    if (g < E) { src = ei[g]; dst = ei[E + g]; }
    else       { src = dst = g - E; }
    atomicAdd(&hist_s[src], 1);
    atomicAdd(&hist_d[dst], 1);
}

// exclusive scan, 16 elems/thread; grid=2: block0 scans hist_s->cur_s,
// block1 scans hist_d->cur_d+off_d (the two scans run concurrently).
#define VPT 16
__global__ __launch_bounds__(1024) void scan_kernel(
    const int* __restrict__ hist_s, int* __restrict__ cur_s,
    const int* __restrict__ hist_d, int* __restrict__ cur_d,
    int* __restrict__ off_d, int n)
{
    const int* hist = blockIdx.x ? hist_d : hist_s;
    int* o0 = blockIdx.x ? cur_d : cur_s;
    int* o1 = blockIdx.x ? off_d : (int*)nullptr;

    __shared__ int warp_sums[16];
    __shared__ int s_carry;
    const int tid  = threadIdx.x;
    const int lane = tid & 63, wid = tid >> 6;
    if (tid == 0) s_carry = 0;
    __syncthreads();
    const int nC = (n + VPT - 1) / VPT;
    for (int base = 0; base < nC; base += 1024) {
        int iC = base + tid;
        int v[VPT];
        bool full = (iC * VPT + VPT <= n);
        if (full) {
            #pragma unroll
            for (int qq = 0; qq < VPT / 4; ++qq)
                *(int4*)&v[qq * 4] = ((const int4*)hist)[iC * (VPT / 4) + qq];
        } else {
            #pragma unroll
            for (int k = 0; k < VPT; ++k)
                v[k] = (iC * VPT + k < n) ? hist[iC * VPT + k] : 0;
        }
        int tsum = 0;
        #pragma unroll
        for (int k = 0; k < VPT; ++k) tsum += v[k];
        int s = tsum;
        #pragma unroll
        for (int dd = 1; dd < 64; dd <<= 1) {
            int t = __shfl_up(s, dd);
            if (lane >= dd) s += t;
        }
        if (lane == 63) warp_sums[wid] = s;
        __syncthreads();
        if (tid < 16) {
            int ws = warp_sums[tid];
            #pragma unroll
            for (int dd = 1; dd < 16; dd <<= 1) {
                int t = __shfl_up(ws, dd);
                if (tid >= dd) ws += t;
            }
            warp_sums[tid] = ws;
        }
        __syncthreads();
        int excl = s_carry + (wid ? warp_sums[wid - 1] : 0) + (s - tsum);
        int o[VPT];
        #pragma unroll
        for (int k = 0; k < VPT; ++k) { o[k] = excl; excl += v[k]; }
        if (full) {
            #pragma unroll
            for (int qq = 0; qq < VPT / 4; ++qq) {
                ((int4*)o0)[iC * (VPT / 4) + qq] = *(int4*)&o[qq * 4];
                if (o1) ((int4*)o1)[iC * (VPT / 4) + qq] = *(int4*)&o[qq * 4];
            }
        } else {
            for (int k = 0; k < VPT; ++k)
                if (iC * VPT + k < n) {
                    o0[iC * VPT + k] = o[k];
                    if (o1) o1[iC * VPT + k] = o[k];
                }
        }
        __syncthreads();
        if (tid == 0) s_carry = s_carry + warp_sums[15];
        __syncthreads();
    }
}

__global__ void scatter_kernel(const int* __restrict__ ei,
                               int* __restrict__ cur_s, int* __restrict__ cur_d,
                               int2* __restrict__ e2,
                               int* __restrict__ ss2, int E, int Et)
{
    int g = blockIdx.x * blockDim.x + threadIdx.x;
    if (g >= Et) return;
    int src, dst;
    if (g < E) { src = ei[g]; dst = ei[E + g]; }
    else       { src = dst = g - E; }
    int ps = atomicAdd(&cur_s[src], 1);
    e2[ps] = make_int2(src, dst);
    int pd = atomicAdd(&cur_d[dst], 1);
    ss2[pd] = src;
}

// ---------------------------------------------------------------------------
// K2: denom, atomic-free. One wave per destination node (contiguous run in
// dst-sorted ss2). Lanes 0..32 = heads. a_src gather software-pipelined one
// iteration deep (issue e+1's row load before e's exp). Writes interleaved
// float2 {a_dst, 1/(denom+eps)} for aggregate's one-load alpha phase.
// ---------------------------------------------------------------------------
__global__ __launch_bounds__(256) void denom_kernel(
    const int* __restrict__ off_d, const int* __restrict__ ss2,
    const float* __restrict__ a_src, const float* __restrict__ a_dstc,
    float* __restrict__ ad2, int N, int Et)
{
    const int d = blockIdx.x * 4 + (threadIdx.x >> 6);
    if (d >= N) return;
    const int lane = threadIdx.x & 63;
    const int beg = off_d[d];
    const int end = (d + 1 < N) ? off_d[d + 1] : Et;
    const float ad = (lane < H_HEADS) ? a_dstc[(size_t)d * H_HEADS + lane] : 0.f;
    float acc = 0.f;
    int src = ss2[beg];
    float vcur = (lane < H_HEADS) ? a_src[(size_t)src * H_HEADS + lane] : 0.f;
    for (int e = beg; e < end; ++e) {
        float vnxt = 0.f;
        if (e + 1 < end) {
            int nxt = ss2[e + 1];
            if (lane < H_HEADS) vnxt = a_src[(size_t)nxt * H_HEADS + lane];
        }
        float v = vcur + ad;
        v = v > 0.f ? v : NEG_SLOPE * v;
        acc += __expf(v);
        vcur = vnxt;
    }
    if (lane < H_HEADS)
        ((float2*)ad2)[(size_t)d * H_HEADS + lane] =
            make_float2(ad, 1.0f / (acc + 1e-16f));
}

// ---------------------------------------------------------------------------
// K3: 64 src-sorted edges/block. Phase 1: 64x33 alphas into LDS (one float2
// load + exp + mul each). Phase 2: 4 lanes/edge, uint2 loads (4 channels per
// lane -> 33 VMEM instrs cover 16 edges/wave). Accumulators are then shfl-
// repacked so each of the 4 wave-atomics covers 4 edges x 16 contiguous
// channels = fully-covered 64B lines (round-4's half-covered sectors doubled
// WRITE_SIZE; this restores full coverage at the lower instruction count).
// ---------------------------------------------------------------------------
#define EPB 64
__global__ __launch_bounds__(256) void aggregate_kernel(
    const int2* __restrict__ e2,
    const float* __restrict__ a_src, const float* __restrict__ ad2,
    const unsigned short* __restrict__ hb,
    float* __restrict__ out, int N, int Et)
{
    __shared__ int   s_src[EPB], s_dst[EPB];
    __shared__ float s_alpha[EPB][H_HEADS];

    // bijective XCD-chunked block swizzle (m204 formula)
    const int nwg = gridDim.x;
    const int q = nwg >> 3, r = nwg & 7;
    const int xcd = blockIdx.x & 7, idx = blockIdx.x >> 3;
    const int bid = (xcd < r ? xcd * (q + 1) : r * (q + 1) + (xcd - r) * q) + idx;

    const int tid = threadIdx.x;
    const int e0  = bid * EPB;
    const size_t segN = (size_t)N * 48;

    if (tid < EPB) {
        int e = e0 + tid;
        int2 v = (e < Et) ? e2[e] : make_int2(0, 0);
        s_src[tid] = v.x; s_dst[tid] = v.y;
    }
    __syncthreads();

    for (int i = tid; i < EPB * H_HEADS; i += 256) {
        int el = i / H_HEADS, hd = i - el * H_HEADS;
        if (e0 + el < Et) {
            int src = s_src[el], dst = s_dst[el];
            float2 di = ((const float2*)ad2)[(size_t)dst * H_HEADS + hd];
            float v = a_src[(size_t)src * H_HEADS + hd] + di.x;
            v = v > 0.f ? v : NEG_SLOPE * v;
            s_alpha[el][hd] = __expf(v) * di.y;
        }
    }
    __syncthreads();

    // phase 2: one edge per thread-quad, 4 channels per lane
    const int el = tid >> 2, cq = tid & 3;
    const int src = s_src[el];
    const unsigned short* hp = hb + (size_t)src * 48 + cq * 4;
    float a0 = 0.f, a1 = 0.f, a2 = 0.f, a3 = 0.f;
    #pragma unroll
    for (int j = 0; j < JG; ++j) {
        const unsigned short* pj = hp + (size_t)j * segN;
        uint2 wA = *(const uint2*)(pj);
        uint2 wB = *(const uint2*)(pj + 16);
        uint2 wC = *(const uint2*)(pj + 32);
        float l0 = s_alpha[el][j * 3 + 0];
        float l1 = s_alpha[el][j * 3 + 1];
        float l2 = s_alpha[el][j * 3 + 2];
        a0 += l0 * bflo(wA.x) + l1 * bflo(wB.x) + l2 * bflo(wC.x);
        a1 += l0 * bfhi(wA.x) + l1 * bfhi(wB.x) + l2 * bfhi(wC.x);
        a2 += l0 * bflo(wA.y) + l1 * bflo(wB.y) + l2 * bflo(wC.y);
        a3 += l0 * bfhi(wA.y) + l1 * bfhi(wB.y) + l2 * bfhi(wC.y);
    }

    // shfl-repack: instr qx covers 4 edges x 16 contiguous channels (64B)
    const int lane  = tid & 63;
    const int wbase = (tid >> 6) * 16;       // first edge of this wave
    #pragma unroll
    for (int qx = 0; qx < 4; ++qx) {
        int S = 16 * qx + ((lane >> 4) << 2) + ((lane & 15) >> 2);
        float s0 = __shfl(a0, S), s1 = __shfl(a1, S);
        float s2 = __shfl(a2, S), s3 = __shfl(a3, S);
        float v = (lane & 2) ? ((lane & 1) ? s3 : s2)
                             : ((lane & 1) ? s1 : s0);
        int elT = wbase + qx * 4 + (lane >> 4);
        if (e0 + elT < Et)
            atomicAdd(&out[s_dst[elT] * C_CH + (lane & 15)], v);
    }
}

// K4: out = tanh(out/H + bias), in place
__global__ void finalize_kernel(float* __restrict__ out,
                                const float* __restrict__ bias, int total)
{
    int g = blockIdx.x * blockDim.x + threadIdx.x;
    if (g >= total) return;
    out[g] = tanhf(out[g] * (1.0f / 33.0f) + bias[g & 15]);
}

// ---------------------------------------------------------------------------
extern "C" void kernel_launch(void* const* d_in, const int* in_sizes, int n_in,
                              void* d_out, int out_size, void* d_ws, size_t ws_size,
                              hipStream_t stream)
{
    const float* x       = (const float*)d_in[0];
    const int*   ei      = (const int*)  d_in[1];
    const float* W       = (const float*)d_in[2];
    const float* att_src = (const float*)d_in[3];
    const float* att_dst = (const float*)d_in[4];
    const float* bias    = (const float*)d_in[5];
    float* out = (float*)d_out;

    const int N  = in_sizes[0] / F_IN;   // 50000
    const int E  = in_sizes[1] / 2;      // 320000
    const int Et = E + N;                // with self loops

    // workspace layout (all 16B-aligned for these sizes)
    unsigned short* hb = (unsigned short*)d_ws;          // 11 segments [N][48]
    float* a_src  = (float*)(hb + (size_t)N * HC);       // [N][33]
    float* a_dstc = a_src + (size_t)N * H_HEADS;         // [N][33] compact a_dst
    float* ad2    = a_dstc + (size_t)N * H_HEADS;        // float2[N][33] a_dst|inv
    int2*  e2     = (int2*)(ad2 + (size_t)N * 66);       // [Et] (src,dst)
    int*   ss2    = (int*)(e2 + Et);
    int*   hist_s = ss2 + Et;
    int*   hist_d = hist_s + N;
    int*   cur_s  = hist_d + N;
    int*   cur_d  = cur_s + N;
    int*   off_d  = cur_d + N;
    unsigned short* Wt = (unsigned short*)(off_d + N);   // [624][128]

    hipMemsetAsync(d_out, 0, (size_t)out_size * sizeof(float), stream);
    hipMemsetAsync(hist_s, 0, 2 * (size_t)N * sizeof(int), stream);  // hist_s + hist_d

    int prepTot = F_IN * HC + 96 * F_IN;
    prep_w_kernel<<<(prepTot + 255) / 256, 256, 0, stream>>>(W, att_src, att_dst, Wt);

    gemm_att_kernel<<<(N + 63) / 64, 256, 0, stream>>>(x, Wt, hb, a_src, a_dstc, N);

    hist_kernel<<<(Et + 255) / 256, 256, 0, stream>>>(ei, hist_s, hist_d, E, Et);
    scan_kernel<<<2, 1024, 0, stream>>>(hist_s, cur_s, hist_d, cur_d, off_d, N);
    scatter_kernel<<<(Et + 255) / 256, 256, 0, stream>>>(ei, cur_s, cur_d,
                                                         e2, ss2, E, Et);

    denom_kernel<<<(N + 3) / 4, 256, 0, stream>>>(off_d, ss2, a_src, a_dstc,
                                                  ad2, N, Et);

    aggregate_kernel<<<(Et + EPB - 1) / EPB, 256, 0, stream>>>(
        e2, a_src, ad2, hb, out, N, Et);

    int totO = N * C_CH;
    finalize_kernel<<<(totO + 255) / 256, 256, 0, stream>>>(out, bias, totO);
}